// Round 1
// baseline (860.056 us; speedup 1.0000x reference)
//
#include <hip/hip_runtime.h>
#include <math.h>

// Problem constants (fixed by the reference)
#define TSEQ 4096
#define NB 8
#define DEM 512
#define HD 64

// 16-lane reductions: the 16 threads sharing a score row are consecutive
// lanes within one wave (tid = ty*16+tx), so xor-shuffles 1,2,4,8 stay inside
// the group.
__device__ __forceinline__ float redmax16(float x) {
#pragma unroll
    for (int off = 1; off < 16; off <<= 1)
        x = fmaxf(x, __shfl_xor(x, off, 64));
    return x;
}

__device__ __forceinline__ float redsum16(float x) {
#pragma unroll
    for (int off = 1; off < 16; off <<= 1)
        x += __shfl_xor(x, off, 64);
    return x;
}

// ---------------------------------------------------------------------------
// QKV projection: [32768 x 512] @ [512 x 64] x3  -> q,k,v in workspace (fp32)
// Block: 256 threads, 64-row M tile, all 192 output cols, K staged 32 at a
// time in LDS. Thread (tx,ty) computes 4 rows x 12 cols in registers.
// ---------------------------------------------------------------------------
__global__ __launch_bounds__(256) void qkv_proj_kernel(
    const float* __restrict__ x,
    const float* __restrict__ Wq,
    const float* __restrict__ Wk,
    const float* __restrict__ Wv,
    float* __restrict__ qo,
    float* __restrict__ ko,
    float* __restrict__ vo)
{
    __shared__ float a_t[32][68];   // A chunk, transposed [k][row]; pitch 68 keeps float4 alignment
    __shared__ float w_s[32][196];  // W chunk, [k][col 0..191] = [Wq|Wk|Wv]

    const int tid = threadIdx.x;
    const int tx = tid & 15;   // 12-col group
    const int ty = tid >> 4;   // 4-row group
    const int r0 = blockIdx.x * 64;

    float acc[4][12];
#pragma unroll
    for (int i = 0; i < 4; ++i)
#pragma unroll
        for (int j = 0; j < 12; ++j) acc[i][j] = 0.f;

    for (int k0 = 0; k0 < DEM; k0 += 32) {
        __syncthreads();
        // Stage A chunk: 64 rows x 32 k = 512 float4, 2 per thread (coalesced)
#pragma unroll
        for (int i = 0; i < 2; ++i) {
            int f = tid + 256 * i;          // < 512
            int row = f >> 3;               // 0..63
            int kk = (f & 7) * 4;           // 0..28
            float4 av = *(const float4*)&x[(r0 + row) * DEM + k0 + kk];
            a_t[kk + 0][row] = av.x;
            a_t[kk + 1][row] = av.y;
            a_t[kk + 2][row] = av.z;
            a_t[kk + 3][row] = av.w;
        }
        // Stage W chunk: 32 k x 192 cols = 1536 float4, 6 per thread
#pragma unroll
        for (int i = 0; i < 6; ++i) {
            int f = tid + 256 * i;          // < 1536
            int kk = f / 48;                // 0..31
            int c4 = (f % 48) * 4;          // 0..188, multiple of 4 (never crosses a matrix)
            int m = c4 >> 6;
            int h = c4 & 63;
            const float* W = (m == 0) ? Wq : ((m == 1) ? Wk : Wv);
            *(float4*)&w_s[kk][c4] = *(const float4*)&W[(k0 + kk) * HD + h];
        }
        __syncthreads();
#pragma unroll 4
        for (int kk = 0; kk < 32; ++kk) {
            float4 a4 = *(const float4*)&a_t[kk][ty * 4];
            float4 w0 = *(const float4*)&w_s[kk][tx * 12 + 0];
            float4 w1 = *(const float4*)&w_s[kk][tx * 12 + 4];
            float4 w2 = *(const float4*)&w_s[kk][tx * 12 + 8];
            float ar[4] = {a4.x, a4.y, a4.z, a4.w};
            float wr[12] = {w0.x, w0.y, w0.z, w0.w,
                            w1.x, w1.y, w1.z, w1.w,
                            w2.x, w2.y, w2.z, w2.w};
#pragma unroll
            for (int i = 0; i < 4; ++i)
#pragma unroll
                for (int j = 0; j < 12; ++j)
                    acc[i][j] = fmaf(ar[i], wr[j], acc[i][j]);
        }
    }

#pragma unroll
    for (int i = 0; i < 4; ++i) {
        int row = r0 + ty * 4 + i;
#pragma unroll
        for (int j4 = 0; j4 < 12; j4 += 4) {
            int c = tx * 12 + j4;
            int m = c >> 6;
            int h = c & 63;
            float* o = (m == 0) ? qo : ((m == 1) ? ko : vo);
            *(float4*)&o[row * HD + h] =
                make_float4(acc[i][j4], acc[i][j4 + 1], acc[i][j4 + 2], acc[i][j4 + 3]);
        }
    }
}

// ---------------------------------------------------------------------------
// Flash attention (fp32, causal). Block = 256 threads = one 64-row q tile of
// one batch. Iterates 64-key tiles up to the diagonal with online softmax.
// Thread (tx,ty) owns a 4x4 micro-tile of S and of O (rows ty*4+, cols tx*4+).
// P round-trips through LDS (aliased onto the K buffer) for the PV matmul.
// ---------------------------------------------------------------------------
__global__ __launch_bounds__(256) void flash_kernel(
    const float* __restrict__ qg,
    const float* __restrict__ kg,
    const float* __restrict__ vg,
    float* __restrict__ out)
{
    __shared__ float q_t[64][68];   // q transposed [d][row], pre-scaled
    __shared__ float k_t[64][68];   // k transposed [d][key]; reused as p[col][row]
    __shared__ float v_s[64][68];   // v natural [key][d]
    auto& p_s = k_t;                // alias: P overwrites K after S is computed

    const int tid = threadIdx.x;
    const int tx = tid & 15;
    const int ty = tid >> 4;
    const int mblk = blockIdx.x;    // q tile index 0..63
    const int b = blockIdx.y;       // batch 0..7
    const int r0 = mblk * 64;
    const float scale = 0.044194173824159216f;  // 512^-0.5 (embed scale!)

    // Stage q transposed, with softmax scale folded in
    const float* qp = qg + (b * TSEQ + r0) * HD;
#pragma unroll
    for (int i = 0; i < 4; ++i) {
        int f = tid + 256 * i;      // < 1024
        int row = f >> 4;           // 0..63
        int dd = (f & 15) * 4;      // 0..60
        float4 qv = *(const float4*)&qp[row * HD + dd];
        q_t[dd + 0][row] = qv.x * scale;
        q_t[dd + 1][row] = qv.y * scale;
        q_t[dd + 2][row] = qv.z * scale;
        q_t[dd + 3][row] = qv.w * scale;
    }

    float mx[4], ln[4], O[4][4];
#pragma unroll
    for (int i = 0; i < 4; ++i) {
        mx[i] = -INFINITY;
        ln[i] = 0.f;
#pragma unroll
        for (int j = 0; j < 4; ++j) O[i][j] = 0.f;
    }

    for (int st = 0; st <= mblk; ++st) {
        const float* kp = kg + (b * TSEQ + st * 64) * HD;
        const float* vp = vg + (b * TSEQ + st * 64) * HD;
        __syncthreads();   // previous PV done reading k_t(=p)/v_s; q_t staged (st=0)
#pragma unroll
        for (int i = 0; i < 4; ++i) {
            int f = tid + 256 * i;
            int key = f >> 4;
            int dd = (f & 15) * 4;
            float4 kv = *(const float4*)&kp[key * HD + dd];
            k_t[dd + 0][key] = kv.x;
            k_t[dd + 1][key] = kv.y;
            k_t[dd + 2][key] = kv.z;
            k_t[dd + 3][key] = kv.w;
            *(float4*)&v_s[key][dd] = *(const float4*)&vp[key * HD + dd];
        }
        __syncthreads();

        // S = (q*scale) @ k^T for this 64x64 tile
        float S[4][4];
#pragma unroll
        for (int i = 0; i < 4; ++i)
#pragma unroll
            for (int j = 0; j < 4; ++j) S[i][j] = 0.f;

#pragma unroll 8
        for (int d = 0; d < 64; ++d) {
            float4 a4 = *(const float4*)&q_t[d][ty * 4];
            float4 c4 = *(const float4*)&k_t[d][tx * 4];
            float ar[4] = {a4.x, a4.y, a4.z, a4.w};
            float cr[4] = {c4.x, c4.y, c4.z, c4.w};
#pragma unroll
            for (int i = 0; i < 4; ++i)
#pragma unroll
                for (int j = 0; j < 4; ++j)
                    S[i][j] = fmaf(ar[i], cr[j], S[i][j]);
        }

        // Causal mask: only the diagonal tile needs it
        if (st == mblk) {
#pragma unroll
            for (int i = 0; i < 4; ++i)
#pragma unroll
                for (int j = 0; j < 4; ++j)
                    if (tx * 4 + j > ty * 4 + i) S[i][j] = -INFINITY;
        }

        __syncthreads();   // all S reads of k_t complete before p overwrites it

        // Online softmax per row; write P (transposed [col][row]) into k_t
#pragma unroll
        for (int i = 0; i < 4; ++i) {
            float rm = fmaxf(fmaxf(S[i][0], S[i][1]), fmaxf(S[i][2], S[i][3]));
            rm = redmax16(rm);
            float mnew = fmaxf(mx[i], rm);
            float al = __expf(mx[i] - mnew);   // exp(-inf)=0 on first tile
            float p0 = __expf(S[i][0] - mnew);
            float p1 = __expf(S[i][1] - mnew);
            float p2 = __expf(S[i][2] - mnew);
            float p3 = __expf(S[i][3] - mnew);
            float rs = redsum16(p0 + p1 + p2 + p3);
            ln[i] = ln[i] * al + rs;
            mx[i] = mnew;
#pragma unroll
            for (int j = 0; j < 4; ++j) O[i][j] *= al;
            p_s[tx * 4 + 0][ty * 4 + i] = p0;
            p_s[tx * 4 + 1][ty * 4 + i] = p1;
            p_s[tx * 4 + 2][ty * 4 + i] = p2;
            p_s[tx * 4 + 3][ty * 4 + i] = p3;
        }
        __syncthreads();

        // O += P @ V
#pragma unroll 8
        for (int c = 0; c < 64; ++c) {
            float4 p4 = *(const float4*)&p_s[c][ty * 4];
            float4 v4 = *(const float4*)&v_s[c][tx * 4];
            float pr[4] = {p4.x, p4.y, p4.z, p4.w};
            float vr[4] = {v4.x, v4.y, v4.z, v4.w};
#pragma unroll
            for (int i = 0; i < 4; ++i)
#pragma unroll
                for (int j = 0; j < 4; ++j)
                    O[i][j] = fmaf(pr[i], vr[j], O[i][j]);
        }
    }

    // Epilogue: normalize and store
#pragma unroll
    for (int i = 0; i < 4; ++i) {
        float inv = 1.0f / ln[i];
        float4 o4 = make_float4(O[i][0] * inv, O[i][1] * inv,
                                O[i][2] * inv, O[i][3] * inv);
        *(float4*)&out[(b * TSEQ + r0 + ty * 4 + i) * HD + tx * 4] = o4;
    }
}

extern "C" void kernel_launch(void* const* d_in, const int* in_sizes, int n_in,
                              void* d_out, int out_size, void* d_ws, size_t ws_size,
                              hipStream_t stream) {
    const float* x  = (const float*)d_in[0];   // [8, 4096, 512]
    const float* Wq = (const float*)d_in[1];   // [512, 64]
    const float* Wk = (const float*)d_in[2];
    const float* Wv = (const float*)d_in[3];
    float* out = (float*)d_out;                // [8, 4096, 64]

    // Workspace: q, k, v fp32, 8*4096*64 floats each = 25.2 MB total
    float* q = (float*)d_ws;
    float* k = q + (size_t)NB * TSEQ * HD;
    float* v = k + (size_t)NB * TSEQ * HD;

    qkv_proj_kernel<<<dim3(NB * TSEQ / 64), 256, 0, stream>>>(x, Wq, Wk, Wv, q, k, v);
    flash_kernel<<<dim3(TSEQ / 64, NB), 256, 0, stream>>>(q, k, v, out);
}

// Round 2
// 207.063 us; speedup vs baseline: 4.1536x; 4.1536x over previous
//
#include <hip/hip_runtime.h>
#include <math.h>

// Problem constants
#define TSEQ 4096
#define NB 8
#define DEM 512
#define HD 64
#define LP 72            // LDS pitch in bf16 elems (144 B): 16B-aligned, 2-way banks (free)
#define QSZ ((size_t)NB * TSEQ * HD)

typedef __attribute__((ext_vector_type(8))) short short8;   // 8 bf16 (4 VGPRs) MFMA frag
typedef __attribute__((ext_vector_type(4))) short short4v;  // 8B packed bf16x4
typedef __attribute__((ext_vector_type(4))) float float4v;  // MFMA C/D frag

// fp32 -> bf16 RNE
__device__ __forceinline__ short f2bf(float f) {
    union { float f; unsigned u; } v; v.f = f;
    unsigned r = v.u + 0x7fffu + ((v.u >> 16) & 1u);
    return (short)(r >> 16);
}

// ---------------------------------------------------------------------------
// W^T precompute: W[512][64] fp32 x3 -> wt[192][512] bf16 (n-major), with the
// softmax scale folded into Wq. One-time-ish (few us), LDS transpose.
// grid = (8 k-chunks, 3 matrices), 256 threads.
// ---------------------------------------------------------------------------
__global__ __launch_bounds__(256) void wtr_kernel(
    const float* __restrict__ Wq, const float* __restrict__ Wk,
    const float* __restrict__ Wv, short* __restrict__ wt)
{
    __shared__ float t[64][65];
    const int tid = threadIdx.x;
    const int k0 = blockIdx.x * 64;
    const int m = blockIdx.y;
    const float* W = (m == 0) ? Wq : ((m == 1) ? Wk : Wv);
    const float sc = (m == 0) ? 0.044194173824159216f : 1.0f;  // 512^-0.5 into Wq

#pragma unroll
    for (int i = 0; i < 4; ++i) {
        int f = tid + 256 * i;           // < 1024
        int k = f >> 4, n4 = (f & 15) * 4;
        float4 wv = *(const float4*)&W[(k0 + k) * HD + n4];
        t[k][n4 + 0] = wv.x; t[k][n4 + 1] = wv.y;
        t[k][n4 + 2] = wv.z; t[k][n4 + 3] = wv.w;
    }
    __syncthreads();
#pragma unroll
    for (int i = 0; i < 4; ++i) {
        int f = tid + 256 * i;
        int n = f >> 4, k4 = (f & 15) * 4;
        short4v o;
        o[0] = f2bf(t[k4 + 0][n] * sc);
        o[1] = f2bf(t[k4 + 1][n] * sc);
        o[2] = f2bf(t[k4 + 2][n] * sc);
        o[3] = f2bf(t[k4 + 3][n] * sc);
        *(short4v*)&wt[(size_t)(m * 64 + n) * DEM + k0 + k4] = o;
    }
}

// ---------------------------------------------------------------------------
// QKV projection via MFMA: computes C^T[n_out][t] = W^T @ X^T per 64-row tile.
// A-frag = W^T rows (contiguous), B-frag = X rows (contiguous). q,k stored
// [b*T+t][64] bf16 (8B packed stores); v stored TRANSPOSED [b][64][T] bf16 so
// the flash kernel's PV B-fragments are contiguous.
// ---------------------------------------------------------------------------
__global__ __launch_bounds__(256) void qkv_mfma(
    const float* __restrict__ x, const short* __restrict__ wt,
    short* __restrict__ q, short* __restrict__ k, short* __restrict__ vt)
{
    __shared__ short xs[64 * LP];    // X chunk bf16 [64 t][64 k]
    __shared__ short ws[192 * LP];   // W^T chunk [192 n][64 k]

    const int tid = threadIdx.x;
    const int w = tid >> 6;
    const int l15 = tid & 15;
    const int quad = (tid >> 4) & 3;
    const int r0 = blockIdx.x * 64;

    float4v acc[12] = {};

    for (int k0 = 0; k0 < DEM; k0 += 64) {
        __syncthreads();
        // stage X (fp32 -> bf16): 4 float4 per thread
#pragma unroll
        for (int i = 0; i < 4; ++i) {
            int f = tid + 256 * i;          // < 1024
            int row = f >> 4, c4 = (f & 15) * 4;
            float4 xv = *(const float4*)&x[(size_t)(r0 + row) * DEM + k0 + c4];
            short4v o;
            o[0] = f2bf(xv.x); o[1] = f2bf(xv.y);
            o[2] = f2bf(xv.z); o[3] = f2bf(xv.w);
            *(short4v*)&xs[row * LP + c4] = o;
        }
        // stage W^T chunk: 6 x 16B per thread
#pragma unroll
        for (int i = 0; i < 6; ++i) {
            int f = tid + 256 * i;          // < 1536
            int n = f >> 3, c = f & 7;
            *(short8*)&ws[n * LP + c * 8] =
                *(const short8*)&wt[(size_t)n * DEM + k0 + c * 8];
        }
        __syncthreads();

#pragma unroll
        for (int kf = 0; kf < 2; ++kf) {
            short8 xb = *(const short8*)&xs[(16 * w + l15) * LP + kf * 32 + quad * 8];
#pragma unroll
            for (int mt = 0; mt < 12; ++mt) {
                short8 wa = *(const short8*)&ws[(mt * 16 + l15) * LP + kf * 32 + quad * 8];
                acc[mt] = __builtin_amdgcn_mfma_f32_16x16x32_bf16(wa, xb, acc[mt], 0, 0, 0);
            }
        }
    }

    // Epilogue. C^T frag: row = n_out = mt*16+quad*4+reg, col = t = 16w+l15.
    const int r = r0 + 16 * w + l15;        // global row (b*T + t)
#pragma unroll
    for (int mt = 0; mt < 8; ++mt) {        // q (mt<4) and k (mt 4..7): packed 8B
        short* dst = (mt < 4) ? q : k;
        short4v o;
        o[0] = f2bf(acc[mt][0]); o[1] = f2bf(acc[mt][1]);
        o[2] = f2bf(acc[mt][2]); o[3] = f2bf(acc[mt][3]);
        *(short4v*)&dst[(size_t)r * HD + (mt & 3) * 16 + quad * 4] = o;
    }
    const int b = r >> 12, t = r & (TSEQ - 1);
#pragma unroll
    for (int mt = 8; mt < 12; ++mt) {       // v transposed: scalar bf16 stores
#pragma unroll
        for (int reg = 0; reg < 4; ++reg) {
            int d = (mt - 8) * 16 + quad * 4 + reg;
            vt[((size_t)(b * HD + d)) * TSEQ + t] = f2bf(acc[mt][reg]);
        }
    }
}

// ---------------------------------------------------------------------------
// Flash attention, bf16 MFMA. One block = one 64-row q tile; LPT descending
// dispatch (heavy diagonal tiles first) for load balance; 2 blocks/CU.
// Computes S^T = K @ Q^T (so per-lane P values share one q-row and pack to
// 8B LDS writes), online softmax, then O = P @ V with V^T-layout B-frags.
// ---------------------------------------------------------------------------
__global__ __launch_bounds__(256, 2) void flash_mfma(
    const short* __restrict__ qw, const short* __restrict__ kw,
    const short* __restrict__ vtw, float* __restrict__ out)
{
    __shared__ short kt[64 * LP];        // K tile [key][d]
    __shared__ short vt[64 * LP];        // V^T tile [d][key]
    __shared__ short pt[4][16 * LP];     // per-wave P [qrow 16][key 64]

    const int tid = threadIdx.x;
    const int w = tid >> 6;
    const int l15 = tid & 15;
    const int quad = (tid >> 4) & 3;
    const int bx = blockIdx.x;
    const int mblk = 63 - (bx >> 3);     // LPT: heavy tiles dispatched first
    const int b = bx & 7;
    const int r0 = mblk * 64;

    // Q B-frags live in registers: rows r0+16w+l15 (q pre-scaled via Wq)
    const short* qrow = qw + ((size_t)(b * TSEQ + r0 + 16 * w + l15)) * HD;
    const short8 qf0 = *(const short8*)(qrow + quad * 8);
    const short8 qf1 = *(const short8*)(qrow + 32 + quad * 8);

    float m_run = -INFINITY, l_run = 0.f;
    float4v O[4] = {};

    const int srow = tid >> 3, sc = tid & 7;   // staging coords
    const short* kbase = kw + (size_t)b * TSEQ * HD;
    const short* vbase = vtw + (size_t)b * HD * TSEQ;

    for (int st = 0; st <= mblk; ++st) {
        __syncthreads();   // all waves done reading kt/vt from previous iter
        {
            const short* kg = kbase + (size_t)(st * 64) * HD;
            const short* vg = vbase + st * 64;
            *(short8*)&kt[srow * LP + sc * 8] = *(const short8*)(kg + srow * HD + sc * 8);
            *(short8*)&kt[(srow + 32) * LP + sc * 8] = *(const short8*)(kg + (srow + 32) * HD + sc * 8);
            *(short8*)&vt[srow * LP + sc * 8] = *(const short8*)(vg + (size_t)srow * TSEQ + sc * 8);
            *(short8*)&vt[(srow + 32) * LP + sc * 8] = *(const short8*)(vg + (size_t)(srow + 32) * TSEQ + sc * 8);
        }
        __syncthreads();

        // S^T = K @ Q^T : 4 key m-tiles x (wave's 16 q-rows)
        float4v S[4] = {};
#pragma unroll
        for (int mt = 0; mt < 4; ++mt) {
            short8 a0 = *(const short8*)&kt[(mt * 16 + l15) * LP + quad * 8];
            short8 a1 = *(const short8*)&kt[(mt * 16 + l15) * LP + 32 + quad * 8];
            S[mt] = __builtin_amdgcn_mfma_f32_16x16x32_bf16(a0, qf0, S[mt], 0, 0, 0);
            S[mt] = __builtin_amdgcn_mfma_f32_16x16x32_bf16(a1, qf1, S[mt], 0, 0, 0);
        }

        // causal mask (diagonal tile only): key > qrow -> -inf
        if (st == mblk) {
            int qg = 16 * w + l15;
#pragma unroll
            for (int mt = 0; mt < 4; ++mt)
#pragma unroll
                for (int r = 0; r < 4; ++r)
                    if (mt * 16 + quad * 4 + r > qg) S[mt][r] = -INFINITY;
        }

        // online softmax for q-row = l15 (keys spread over reg x mtile x quad)
        float mx = S[0][0];
#pragma unroll
        for (int mt = 0; mt < 4; ++mt)
#pragma unroll
            for (int r = 0; r < 4; ++r) mx = fmaxf(mx, S[mt][r]);
        mx = fmaxf(mx, __shfl_xor(mx, 16, 64));
        mx = fmaxf(mx, __shfl_xor(mx, 32, 64));
        float mnew = fmaxf(m_run, mx);
        float alpha = __expf(m_run - mnew);   // exp(-inf)=0 first iter
        float rs = 0.f;
#pragma unroll
        for (int mt = 0; mt < 4; ++mt)
#pragma unroll
            for (int r = 0; r < 4; ++r) {
                float p = __expf(S[mt][r] - mnew);
                S[mt][r] = p;
                rs += p;
            }
        rs += __shfl_xor(rs, 16, 64);
        rs += __shfl_xor(rs, 32, 64);
        l_run = l_run * alpha + rs;
        m_run = mnew;

        // rescale O (O rows = quad*4+reg; alpha lives at lane l15==row)
#pragma unroll
        for (int r = 0; r < 4; ++r) {
            float ar = __shfl(alpha, quad * 4 + r, 64);
#pragma unroll
            for (int nt = 0; nt < 4; ++nt) O[nt][r] *= ar;
        }

        // write P (bf16) to wave-private LDS, row-major [qrow][key]
#pragma unroll
        for (int mt = 0; mt < 4; ++mt) {
            short4v pk;
            pk[0] = f2bf(S[mt][0]); pk[1] = f2bf(S[mt][1]);
            pk[2] = f2bf(S[mt][2]); pk[3] = f2bf(S[mt][3]);
            *(short4v*)&pt[w][l15 * LP + mt * 16 + quad * 4] = pk;
        }

        // O += P @ V  (A = P rows, B = V^T rows: both contiguous b128 reads)
#pragma unroll
        for (int kf = 0; kf < 2; ++kf) {
            short8 pa = *(const short8*)&pt[w][l15 * LP + kf * 32 + quad * 8];
#pragma unroll
            for (int nt = 0; nt < 4; ++nt) {
                short8 vb = *(const short8*)&vt[(nt * 16 + l15) * LP + kf * 32 + quad * 8];
                O[nt] = __builtin_amdgcn_mfma_f32_16x16x32_bf16(pa, vb, O[nt], 0, 0, 0);
            }
        }
    }

    // epilogue: normalize, store fp32. O frag: row = quad*4+reg, col = nt*16+l15
    float inv = 1.0f / l_run;
#pragma unroll
    for (int r = 0; r < 4; ++r) {
        float ir = __shfl(inv, quad * 4 + r, 64);
        size_t row = (size_t)(b * TSEQ + r0 + 16 * w + quad * 4 + r) * HD;
#pragma unroll
        for (int nt = 0; nt < 4; ++nt)
            out[row + nt * 16 + l15] = O[nt][r] * ir;
    }
}

extern "C" void kernel_launch(void* const* d_in, const int* in_sizes, int n_in,
                              void* d_out, int out_size, void* d_ws, size_t ws_size,
                              hipStream_t stream) {
    const float* x  = (const float*)d_in[0];   // [8, 4096, 512]
    const float* Wq = (const float*)d_in[1];   // [512, 64]
    const float* Wk = (const float*)d_in[2];
    const float* Wv = (const float*)d_in[3];
    float* out = (float*)d_out;                // [8, 4096, 64] fp32

    short* q  = (short*)d_ws;                  // bf16 [8*4096][64], pre-scaled
    short* k  = q + QSZ;                       // bf16 [8*4096][64]
    short* vt = k + QSZ;                       // bf16 [8][64][4096] (transposed)
    short* wt = vt + QSZ;                      // bf16 W^T [192][512]

    wtr_kernel<<<dim3(8, 3), 256, 0, stream>>>(Wq, Wk, Wv, wt);
    qkv_mfma<<<dim3(NB * TSEQ / 64), 256, 0, stream>>>(x, wt, q, k, vt);
    flash_mfma<<<dim3(512), 256, 0, stream>>>(q, k, vt, out);
}